// Round 1
// baseline (207.444 us; speedup 1.0000x reference)
//
#include <hip/hip_runtime.h>

// RoiAlign fused: level-select + crop_and_resize(7x7 bilinear, extrap 0)
// feat0: [B,256,256,256] f32 NHWC ; feat1: [B,128,128,256] f32 ; rois: [B,R,5]
// out: [B,R,7,7,256] f32
//
// Mapping: one wave (64 lanes) per (box n, pool pos i,j); lane -> 4 channels
// via float4. All global accesses are 16B/lane coalesced.

#define POOL 7
#define NCH 256

__global__ __launch_bounds__(256) void roialign_kernel(
    const float* __restrict__ feat0,
    const float* __restrict__ feat1,
    const float* __restrict__ rois,
    float* __restrict__ out,
    int NB, int R) // NB = B*R
{
    int t = blockIdx.x * blockDim.x + threadIdx.x;
    int lane = t & 63;          // channel group: channels [4*lane, 4*lane+3]
    int wid  = t >> 6;          // n*49 + pos
    int n    = wid / 49;
    if (n >= NB) return;
    int pos  = wid - n * 49;
    int i = pos / POOL;
    int j = pos - i * POOL;

    const float* roi = rois + (size_t)n * 5;
    float y1 = roi[0], x1 = roi[1], y2 = roi[2], x2 = roi[3];

    // level select on RAW box coords (before normalization), matching ref
    bool lvl = (y2 - y1 > 48.0f) || (x2 - x1 > 48.0f);
    const float* feat = lvl ? feat1 : feat0;
    int H = lvl ? 128 : 256;
    int W = H;
    int b = n / R;

    const float inv_img = 1.0f / 1024.0f;
    float y1n = y1 * inv_img, y2n = y2 * inv_img;
    float x1n = x1 * inv_img, x2n = x2 * inv_img;

    // ys = (y1n + (i/6)*(y2n-y1n)) * (H-1)   -- same op order as reference
    float ry = (float)i / 6.0f;
    float rx = (float)j / 6.0f;
    float ys = (y1n + ry * (y2n - y1n)) * (float)(H - 1);
    float xs = (x1n + rx * (x2n - x1n)) * (float)(W - 1);

    float y0f = floorf(ys), x0f = floorf(xs);
    float wy = ys - y0f;
    float wx = xs - x0f;

    // clip in float, then cast (matches jnp.clip(...).astype(int32))
    float Hm1 = (float)(H - 1), Wm1 = (float)(W - 1);
    int y0 = (int)fminf(fmaxf(y0f,        0.0f), Hm1);
    int yp = (int)fminf(fmaxf(y0f + 1.0f, 0.0f), Hm1);
    int x0 = (int)fminf(fmaxf(x0f,        0.0f), Wm1);
    int xp = (int)fminf(fmaxf(x0f + 1.0f, 0.0f), Wm1);

    bool valid = (ys >= 0.0f) && (ys <= Hm1) && (xs >= 0.0f) && (xs <= Wm1);

    size_t plane = (size_t)b * H * W;
    size_t r0 = (plane + (size_t)y0 * W) * NCH;
    size_t r1 = (plane + (size_t)yp * W) * NCH;
    int coff = lane * 4;

    const float4* p00 = (const float4*)(feat + r0 + (size_t)x0 * NCH + coff);
    const float4* p01 = (const float4*)(feat + r0 + (size_t)xp * NCH + coff);
    const float4* p10 = (const float4*)(feat + r1 + (size_t)x0 * NCH + coff);
    const float4* p11 = (const float4*)(feat + r1 + (size_t)xp * NCH + coff);

    float4 v00 = *p00, v01 = *p01, v10 = *p10, v11 = *p11;

    float wx1 = 1.0f - wx, wy1 = 1.0f - wy;
    float4 o;
    {
        float top_x = v00.x * wx1 + v01.x * wx;
        float bot_x = v10.x * wx1 + v11.x * wx;
        o.x = top_x * wy1 + bot_x * wy;
        float top_y = v00.y * wx1 + v01.y * wx;
        float bot_y = v10.y * wx1 + v11.y * wx;
        o.y = top_y * wy1 + bot_y * wy;
        float top_z = v00.z * wx1 + v01.z * wx;
        float bot_z = v10.z * wx1 + v11.z * wx;
        o.z = top_z * wy1 + bot_z * wy;
        float top_w = v00.w * wx1 + v01.w * wx;
        float bot_w = v10.w * wx1 + v11.w * wx;
        o.w = top_w * wy1 + bot_w * wy;
    }
    if (!valid) { o.x = 0.0f; o.y = 0.0f; o.z = 0.0f; o.w = 0.0f; }

    float4* po = (float4*)(out + ((size_t)n * 49 + pos) * NCH + coff);
    *po = o;
}

extern "C" void kernel_launch(void* const* d_in, const int* in_sizes, int n_in,
                              void* d_out, int out_size, void* d_ws, size_t ws_size,
                              hipStream_t stream) {
    const float* feat0 = (const float*)d_in[0];
    const float* feat1 = (const float*)d_in[1];
    const float* rois  = (const float*)d_in[2];
    float* out = (float*)d_out;

    // B from feat0 size [B,256,256,256]; R from rois size [B,R,5]
    int B  = in_sizes[0] / (256 * 256 * 256);
    int NB = in_sizes[2] / 5;        // B*R boxes
    int R  = NB / B;

    // one wave per (box, pool position): NB*49 waves, 64 lanes each
    long long threads = (long long)NB * 49 * 64;
    int block = 256;
    int grid = (int)((threads + block - 1) / block);
    roialign_kernel<<<grid, block, 0, stream>>>(feat0, feat1, rois, out, NB, R);
}